// Round 1
// baseline (175.436 us; speedup 1.0000x reference)
//
#include <hip/hip_runtime.h>
#include <stdint.h>
#include <stddef.h>

typedef _Float16 f16;
typedef __attribute__((ext_vector_type(8))) _Float16 f16x8;
typedef __attribute__((ext_vector_type(4))) _Float16 f16x4;
typedef __attribute__((ext_vector_type(16))) float f32x16;
typedef __attribute__((ext_vector_type(4))) float floatx4;

#define MFMA(a, b, c) __builtin_amdgcn_mfma_f32_32x32x16_f16((a), (b), (c), 0, 0, 0)

typedef const __attribute__((address_space(1))) void gvoid_t;
typedef __attribute__((address_space(3))) void svoid_t;

__device__ __forceinline__ void gload_lds16(const void* g, void* l) {
  // wave-uniform LDS base; HW writes lane's 16B at base + lane*16
  __builtin_amdgcn_global_load_lds((gvoid_t*)g, (svoid_t*)l, 16, 0, 0);
}

// ---------------- fp32 -> fp16 convert ----------------
__global__ __launch_bounds__(256) void k_cvt_f16(const float* __restrict__ in,
                                                 f16* __restrict__ out, int n4) {
  int i = blockIdx.x * 256 + threadIdx.x;
  if (i < n4) {
    floatx4 v = ((const floatx4*)in)[i];
    f16x4 o;
    o[0] = (f16)v[0]; o[1] = (f16)v[1]; o[2] = (f16)v[2]; o[3] = (f16)v[3];
    ((f16x4*)out)[i] = o;
  }
}

// ---------------- W (KxN) fp32 -> Wt (NxK) fp16, LDS tiled ----------------
__global__ __launch_bounds__(256) void k_transpose_cvt(const float* __restrict__ W,
                                                       f16* __restrict__ Wt, int K, int N) {
  __shared__ float t[32][33];
  int k0 = blockIdx.x * 32, n0 = blockIdx.y * 32;
  int tx = threadIdx.x & 31, ty = threadIdx.x >> 5;  // 32 x 8
#pragma unroll
  for (int i = 0; i < 4; ++i)
    t[ty + 8 * i][tx] = W[(size_t)(k0 + ty + 8 * i) * N + n0 + tx];
  __syncthreads();
#pragma unroll
  for (int i = 0; i < 4; ++i)
    Wt[(size_t)(n0 + ty + 8 * i) * K + k0 + tx] = (f16)t[tx][ty + 8 * i];
}

// ---------------- generic fp16 GEMM: C(MxN,f32) = A(MxK) * Bt(NxK)^T ----------------
// tile 128x128, BK=64, 4 waves (2x2 of 64x64), mfma 32x32x16 f16.
__global__ __launch_bounds__(256, 2) void k_gemm(const f16* __restrict__ A,
                                                 const f16* __restrict__ Bt,
                                                 float* __restrict__ C,
                                                 int M, int N, int K) {
  __shared__ __align__(16) f16 As[128 * 64];
  __shared__ __align__(16) f16 Bs[128 * 64];
  int tid = threadIdx.x;
  int wave = tid >> 6, lane = tid & 63;
  int m0 = blockIdx.y * 128, n0 = blockIdx.x * 128;
  int wm = (wave >> 1) * 64, wn = (wave & 1) * 64;
  int rl = lane & 31, h = lane >> 5;
  int srow = lane >> 3;   // row within 8-row chunk
  int sslot = lane & 7;   // 16B slot within 128B row

  f32x16 acc[2][2];
#pragma unroll
  for (int mb = 0; mb < 2; ++mb)
#pragma unroll
    for (int nb = 0; nb < 2; ++nb)
#pragma unroll
      for (int r = 0; r < 16; ++r) acc[mb][nb][r] = 0.f;

  for (int k0 = 0; k0 < K; k0 += 64) {
    __syncthreads();  // protect LDS from previous iteration's readers
#pragma unroll
    for (int c = 0; c < 4; ++c) {
      int chunk = c * 4 + wave;           // 0..15, wave-uniform
      int r = chunk * 8 + srow;           // 0..127
      int cb = sslot ^ (r & 7);           // pre-swizzled source col-block
      gload_lds16(A + (size_t)(m0 + r) * K + k0 + cb * 8, As + chunk * 512);
      gload_lds16(Bt + (size_t)(n0 + r) * K + k0 + cb * 8, Bs + chunk * 512);
    }
    __syncthreads();  // drains vmcnt -> staged data visible

#pragma unroll
    for (int kb = 0; kb < 4; ++kb) {
      int s = 2 * kb + h;
      f16x8 af[2], bf[2];
#pragma unroll
      for (int mb = 0; mb < 2; ++mb) {
        int r = wm + mb * 32 + rl;
        af[mb] = *(const f16x8*)(As + r * 64 + (s ^ (r & 7)) * 8);
      }
#pragma unroll
      for (int nb = 0; nb < 2; ++nb) {
        int r = wn + nb * 32 + rl;
        bf[nb] = *(const f16x8*)(Bs + r * 64 + (s ^ (r & 7)) * 8);
      }
#pragma unroll
      for (int mb = 0; mb < 2; ++mb)
#pragma unroll
        for (int nb = 0; nb < 2; ++nb)
          acc[mb][nb] = MFMA(af[mb], bf[nb], acc[mb][nb]);
    }
  }

#pragma unroll
  for (int mb = 0; mb < 2; ++mb)
#pragma unroll
    for (int nb = 0; nb < 2; ++nb)
#pragma unroll
      for (int r = 0; r < 16; ++r) {
        int i = m0 + wm + mb * 32 + (r & 3) + 8 * (r >> 2) + 4 * h;
        int j = n0 + wn + nb * 32 + rl;
        C[(size_t)i * N + j] = acc[mb][nb][r];
      }
}

// ---------------- RoPE + split + cvt to fp16 ----------------
// Cp: (16384 x 640) f32 = [q1 q2 k1 k2 v] blocks of 128 cols
__global__ __launch_bounds__(256) void k_rope(const float* __restrict__ Cp,
                                              const float* __restrict__ cosp,
                                              const float* __restrict__ sinp,
                                              f16* __restrict__ q1h, f16* __restrict__ q2h,
                                              f16* __restrict__ k1h, f16* __restrict__ k2h,
                                              f16* __restrict__ vh) {
  int row = blockIdx.x * 4 + (threadIdx.x >> 6);
  int d = threadIdx.x & 63;
  int s = row & 4095;
  float c = cosp[s * 64 + d], sn = sinp[s * 64 + d];
  const float* rp = Cp + (size_t)row * 640;
  f16* outs[4] = {q1h, q2h, k1h, k2h};
#pragma unroll
  for (int m = 0; m < 4; ++m) {
    float a = rp[m * 128 + d];
    float b = rp[m * 128 + 64 + d];
    outs[m][(size_t)row * 128 + d]      = (f16)(a * c - b * sn);
    outs[m][(size_t)row * 128 + 64 + d] = (f16)(a * sn + b * c);
  }
  vh[(size_t)row * 128 + d]      = (f16)rp[512 + d];
  vh[(size_t)row * 128 + 64 + d] = (f16)rp[512 + 64 + d];
}

// ---------------- bilinear causal attention ----------------
// O = (mask ∘ ((Q1K1^T)*(Q2K2^T)/128)) V, per batch. 32-row blocks,
// 4 waves per block split key-tiles round-robin, LDS reduce at end.
__global__ __launch_bounds__(256, 2) void k_attn(const f16* __restrict__ q1h,
                                                 const f16* __restrict__ q2h,
                                                 const f16* __restrict__ k1h,
                                                 const f16* __restrict__ k2h,
                                                 const f16* __restrict__ vh,
                                                 f16* __restrict__ oh) {
  __shared__ __align__(16) f16 P[4][32][40];  // per-wave, 80B rows -> conflict-free b128 reads
  __shared__ float Osum[32][128];
  int idx = blockIdx.x;
  int b = idx & 3;
  int pr = (idx & 255) >> 2;                  // 0..63
  int rb = (idx < 256) ? (127 - pr) : pr;     // complementary work pairing across dispatch
  int wave = threadIdx.x >> 6, lane = threadIdx.x & 63;
  int rl = lane & 31, h = lane >> 5;
  size_t base = (size_t)b * 4096 * 128;
  int i0 = rb * 32;

  for (int e = threadIdx.x; e < 32 * 128; e += 256) ((float*)Osum)[e] = 0.f;

  // Q fragments held in registers for the whole key loop
  f16x8 qa[8], qb[8];
  {
    const f16* p1 = q1h + base + (size_t)(i0 + rl) * 128 + 8 * h;
    const f16* p2 = q2h + base + (size_t)(i0 + rl) * 128 + 8 * h;
#pragma unroll
    for (int kb = 0; kb < 8; ++kb) {
      qa[kb] = *(const f16x8*)(p1 + kb * 16);
      qb[kb] = *(const f16x8*)(p2 + kb * 16);
    }
  }

  f32x16 oacc[4];
#pragma unroll
  for (int nb = 0; nb < 4; ++nb)
#pragma unroll
    for (int r = 0; r < 16; ++r) oacc[nb][r] = 0.f;

  const float scale2 = 1.0f / 128.0f;

  for (int jt = wave; jt <= rb; jt += 4) {
    int j0 = jt * 32;
    const f16* p1 = k1h + base + (size_t)(j0 + rl) * 128 + 8 * h;
    const f16* p2 = k2h + base + (size_t)(j0 + rl) * 128 + 8 * h;

    // V B-fragments: lane gathers its column (d = nb*32+rl) for 8 consecutive j.
    // Per (nb,kv,i) the 64 lanes form two fully-coalesced 64B segments.
    f16x8 vf[4][2];
#pragma unroll
    for (int nb = 0; nb < 4; ++nb)
#pragma unroll
      for (int kv = 0; kv < 2; ++kv) {
        const f16* vp = vh + base + (size_t)(j0 + kv * 16 + 8 * h) * 128 + nb * 32 + rl;
#pragma unroll
        for (int i = 0; i < 8; ++i) vf[nb][kv][i] = vp[i * 128];
      }

    f32x16 s1, s2;
#pragma unroll
    for (int r = 0; r < 16; ++r) { s1[r] = 0.f; s2[r] = 0.f; }
#pragma unroll
    for (int kb = 0; kb < 8; ++kb) {
      f16x8 kf1 = *(const f16x8*)(p1 + kb * 16);
      f16x8 kf2 = *(const f16x8*)(p2 + kb * 16);
      s1 = MFMA(qa[kb], kf1, s1);
      s2 = MFMA(qb[kb], kf2, s2);
    }

    bool diag = (jt == rb);
#pragma unroll
    for (int r = 0; r < 16; ++r) {
      int irow = (r & 3) + 8 * (r >> 2) + 4 * h;  // local query row
      float p = s1[r] * s2[r] * scale2;
      if (diag && rl > irow) p = 0.f;             // causal: zero where j > i
      P[wave][irow][rl] = (f16)p;
    }
    // same-wave DS ordering: write->read handled by in-order DS pipe + compiler waits
#pragma unroll
    for (int kv = 0; kv < 2; ++kv) {
      f16x8 pf = *(const f16x8*)(&P[wave][rl][kv * 16 + 8 * h]);
#pragma unroll
      for (int nb = 0; nb < 4; ++nb)
        oacc[nb] = MFMA(pf, vf[nb][kv], oacc[nb]);
    }
  }

  // cross-wave reduction of partial O
  __syncthreads();
  for (int w = 0; w < 4; ++w) {
    if (wave == w) {
#pragma unroll
      for (int nb = 0; nb < 4; ++nb)
#pragma unroll
        for (int r = 0; r < 16; ++r) {
          int irow = (r & 3) + 8 * (r >> 2) + 4 * h;
          Osum[irow][nb * 32 + rl] += oacc[nb][r];
        }
    }
    __syncthreads();
  }
  for (int e = threadIdx.x; e < 4096; e += 256) {
    int i = e >> 7, d = e & 127;
    oh[base + (size_t)(i0 + i) * 128 + d] = (f16)Osum[i][d];
  }
}

// ---------------- launch ----------------
extern "C" void kernel_launch(void* const* d_in, const int* in_sizes, int n_in,
                              void* d_out, int out_size, void* d_ws, size_t ws_size,
                              hipStream_t stream) {
  (void)in_sizes; (void)n_in; (void)out_size; (void)ws_size;
  const float* x  = (const float*)d_in[0];
  const float* cp = (const float*)d_in[1];
  const float* sp = (const float*)d_in[2];
  // d_in[3] = causal_mask (unused; mask computed analytically)
  const float* W[5] = {(const float*)d_in[4], (const float*)d_in[5], (const float*)d_in[6],
                       (const float*)d_in[7], (const float*)d_in[8]};
  const float* Wo = (const float*)d_in[9];
  float* out = (float*)d_out;
  char* ws = (char*)d_ws;

  // workspace layout (bytes)
  const size_t OFF_XH    = 0;                      // 16384*1024*2 = 33554432
  const size_t OFF_WTH   = 33554432;               // 640*1024*2   = 1310720
  const size_t OFF_WOTH  = OFF_WTH + 1310720;      // 1024*128*2   = 262144
  const size_t OFF_CPROJ = OFF_WOTH + 262144;      // 16384*640*4  = 41943040
  const size_t OFF_H     = OFF_CPROJ + 41943040;   // 6 x 16384*128*2 (q1,q2,k1,k2,v,o)
  f16*   xh    = (f16*)(ws + OFF_XH);
  f16*   Wth   = (f16*)(ws + OFF_WTH);
  f16*   Woth  = (f16*)(ws + OFF_WOTH);
  float* Cproj = (float*)(ws + OFF_CPROJ);
  f16*   q1h   = (f16*)(ws + OFF_H + 0 * 4194304);
  f16*   q2h   = (f16*)(ws + OFF_H + 1 * 4194304);
  f16*   k1h   = (f16*)(ws + OFF_H + 2 * 4194304);
  f16*   k2h   = (f16*)(ws + OFF_H + 3 * 4194304);
  f16*   vh    = (f16*)(ws + OFF_H + 4 * 4194304);
  f16*   oh    = (f16*)(ws + OFF_H + 5 * 4194304);

  // 1) x -> fp16
  k_cvt_f16<<<16384, 256, 0, stream>>>(x, xh, 4194304);
  // 2) weight transposes (fp32 KxN -> fp16 NxK)
  for (int w = 0; w < 5; ++w)
    k_transpose_cvt<<<dim3(32, 4), 256, 0, stream>>>(W[w], Wth + (size_t)w * 128 * 1024, 1024, 128);
  k_transpose_cvt<<<dim3(4, 32), 256, 0, stream>>>(Wo, Woth, 128, 1024);
  // 3) fused projection GEMM: (16384x1024) @ (1024x640) -> fp32
  k_gemm<<<dim3(5, 128), 256, 0, stream>>>(xh, Wth, Cproj, 16384, 640, 1024);
  // 4) RoPE + cvt
  k_rope<<<4096, 256, 0, stream>>>(Cproj, cp, sp, q1h, q2h, k1h, k2h, vh);
  // 5) bilinear causal attention
  k_attn<<<512, 256, 0, stream>>>(q1h, q2h, k1h, k2h, vh, oh);
  // 6) output projection: (16384x128) @ (128x1024) -> d_out fp32
  k_gemm<<<dim3(8, 128), 256, 0, stream>>>(oh, Woth, out, 16384, 1024, 128);
}